// Round 2
// baseline (293.042 us; speedup 1.0000x reference)
//
#include <hip/hip_runtime.h>
#include <stdint.h>

// ---------------------------------------------------------------------------
// Compile-time tables + fragment-packed bf16 constant B matrices.
// SYN = Y' [K=64 (36 real) x N=160 (144 real grid pts)]   (synthesis, to_grid)
// ANA = Yw' [K=160 (144 real) x N=48 (36 real coeffs)]    (analysis, from_grid)
// Packed per MFMA 16x16x32 B-fragment: B[k=quad*8+j][n=lane&15].
// ---------------------------------------------------------------------------
namespace ct {

constexpr double PI_ = 3.14159265358979323846;

constexpr double csqrt(double x) {
  double g = x > 1.0 ? x : 1.0;
  for (int i = 0; i < 40; ++i) g = 0.5 * (g + x / g);
  return g;
}
constexpr double ccos(double x) {  // |x| <= pi
  double x2 = x * x, t = 1.0, s = 1.0;
  for (int k = 1; k <= 16; ++k) { t *= -x2 / ((2.0 * k - 1.0) * (2.0 * k)); s += t; }
  return s;
}
constexpr double csin(double x) {  // |x| <= pi
  double x2 = x * x, t = x, s = x;
  for (int k = 1; k <= 16; ++k) { t *= -x2 / ((2.0 * k) * (2.0 * k + 1.0)); s += t; }
  return s;
}

struct GL { double x[12]; double w[12]; };

constexpr GL gl12() {
  GL g{};
  for (int i = 0; i < 12; ++i) {
    double x = ccos(PI_ * (i + 0.75) / 12.5);
    for (int it = 0; it < 50; ++it) {
      double p0 = 1.0, p1 = x;
      for (int k = 2; k <= 12; ++k) { double pk = ((2.0 * k - 1.0) * x * p1 - (k - 1.0) * p0) / k; p0 = p1; p1 = pk; }
      double dp = 12.0 * (x * p1 - p0) / (x * x - 1.0);
      x -= p1 / dp;
    }
    double p0 = 1.0, p1 = x;
    for (int k = 2; k <= 12; ++k) { double pk = ((2.0 * k - 1.0) * x * p1 - (k - 1.0) * p0) / k; p0 = p1; p1 = pk; }
    double dp = 12.0 * (x * p1 - p0) / (x * x - 1.0);
    g.x[i] = x;
    g.w[i] = 2.0 / ((1.0 - x * x) * dp * dp);
  }
  return g;
}

struct Tab {
  double PA[12][36];   // Pbar_l^{|m|}(x_b) by SH index k
  double PB[12][36];   // PA * wq[b] * (2*pi/12)
  double ANG[12][36];  // angular factor at alpha_a for SH index k
};

constexpr Tab make_tab() {
  Tab t{};
  GL g = gl12();
  for (int b = 0; b < 12; ++b) {
    double x = g.x[b];
    double s = csqrt(1.0 - x * x);
    double P[6][6] = {};
    P[0][0] = csqrt(1.0 / (4.0 * PI_));
    for (int m = 1; m <= 5; ++m) P[m][m] = csqrt((2.0 * m + 1.0) / (2.0 * m)) * s * P[m - 1][m - 1];
    for (int m = 0; m < 5; ++m)  P[m + 1][m] = csqrt(2.0 * m + 3.0) * x * P[m][m];
    for (int m = 0; m <= 5; ++m)
      for (int l = m + 2; l <= 5; ++l) {
        double aa = csqrt((4.0 * l * l - 1.0) / (double)(l * l - m * m));
        double bb = csqrt(((l - 1.0) * (l - 1.0) - (double)(m * m)) / (4.0 * (l - 1.0) * (l - 1.0) - 1.0));
        P[l][m] = aa * (x * P[l - 1][m] - bb * P[l - 2][m]);
      }
    for (int l = 0; l <= 5; ++l)
      for (int m = -l; m <= l; ++m) {
        int k = l * l + l + m, am = m < 0 ? -m : m;
        t.PA[b][k] = P[l][am];
        t.PB[b][k] = P[l][am] * g.w[b] * (2.0 * PI_ / 12.0);
      }
  }
  double r2 = csqrt(2.0);
  for (int a = 0; a < 12; ++a)
    for (int l = 0; l <= 5; ++l)
      for (int m = -l; m <= l; ++m) {
        int k = l * l + l + m, am = m < 0 ? -m : m;
        double v = 1.0;
        if (m != 0) {
          int qq = (am * a) % 12;  // exact angle reduction: angle = 2*pi*qq/12
          double ang = 2.0 * PI_ * qq / 12.0;
          if (ang > PI_) ang -= 2.0 * PI_;
          v = (m > 0) ? r2 * ccos(ang) : r2 * csin(ang);
        }
        t.ANG[a][k] = v;
      }
  return t;
}

constexpr Tab TD = make_tab();

// float -> bf16 bit pattern (round-to-nearest-even), pure-arithmetic constexpr.
constexpr unsigned f2bf(double x) {
  if (x == 0.0) return 0u;
  unsigned s = 0u; double a = x;
  if (a < 0.0) { s = 0x8000u; a = -a; }
  int e = 127;
  while (a >= 2.0) { a *= 0.5; ++e; }
  while (a < 1.0)  { a *= 2.0; --e; }
  double md = (a - 1.0) * 128.0;
  int mi = (int)md;
  double fr = md - mi;
  if (fr > 0.5 || (fr == 0.5 && (mi & 1))) ++mi;
  if (mi == 128) { mi = 0; ++e; }
  return s | ((unsigned)e << 7) | (unsigned)mi;
}

constexpr double syn_val(int k, int n) {  // Y'[k][n], n = b*12 + a
  if (k >= 36 || n >= 144) return 0.0;
  int b = n / 12, a = n % 12;
  return TD.PA[b][k] * TD.ANG[a][k];
}
constexpr double ana_val(int kp, int np) {  // Yw'[kp][np], kp = b*12 + a
  if (kp >= 144 || np >= 36) return 0.0;
  int b = kp / 12, a = kp % 12;
  return TD.PB[b][np] * TD.ANG[a][np];
}

struct alignas(16) SynArr { unsigned v[2 * 10 * 64 * 4]; };  // 20 KB
struct alignas(16) AnaArr { unsigned v[5 * 3 * 64 * 4]; };   // 15 KB

constexpr SynArr make_syn() {
  SynArr F{};
  for (int ks = 0; ks < 2; ++ks)
    for (int nt = 0; nt < 10; ++nt)
      for (int lane = 0; lane < 64; ++lane)
        for (int jp = 0; jp < 4; ++jp) {
          int q = lane >> 4, l16 = lane & 15;
          int k0 = ks * 32 + q * 8 + jp * 2;
          int n = nt * 16 + l16;
          F.v[((ks * 10 + nt) * 64 + lane) * 4 + jp] =
              f2bf(syn_val(k0, n)) | (f2bf(syn_val(k0 + 1, n)) << 16);
        }
  return F;
}
constexpr AnaArr make_ana() {
  AnaArr F{};
  for (int ks = 0; ks < 5; ++ks)
    for (int nt = 0; nt < 3; ++nt)
      for (int lane = 0; lane < 64; ++lane)
        for (int jp = 0; jp < 4; ++jp) {
          int q = lane >> 4, l16 = lane & 15;
          int k0 = ks * 32 + q * 8 + jp * 2;
          int n = nt * 16 + l16;
          F.v[((ks * 3 + nt) * 64 + lane) * 4 + jp] =
              f2bf(ana_val(k0, n)) | (f2bf(ana_val(k0 + 1, n)) << 16);
        }
  return F;
}

}  // namespace ct

__device__ constexpr ct::SynArr SYNB = ct::make_syn();
__device__ constexpr ct::AnaArr ANAB = ct::make_ana();

typedef __attribute__((ext_vector_type(8))) short short8;
typedef __attribute__((ext_vector_type(4))) float f32x4;

#define STRC 80    // CO row stride (ushorts): 160 B, 16B-aligned
#define STRG 168   // G row stride (ushorts): 336 B, 16B-aligned

__device__ __forceinline__ unsigned short bfr(float x) {  // round-to-nearest bf16
  return (unsigned short)((__float_as_uint(x) + 0x8000u) >> 16);
}
__device__ __forceinline__ float bf2f(unsigned short u) {
  return __uint_as_float(((unsigned)u) << 16);
}
constexpr int lk(int k) { return k >= 25 ? 5 : k >= 16 ? 4 : k >= 9 ? 3 : k >= 4 ? 2 : k >= 1 ? 1 : 0; }

template <int KB>
__device__ __forceinline__ void epilogue_half(int r, const float* fp, float* op,
                                              const unsigned short* CO, const float* Gf,
                                              const float wn0[6], const float wn1[6], const float wn2[6]) {
#pragma unroll
  for (int p = 0; p < 9; ++p) {
    const int k0 = KB + 2 * p, k1 = k0 + 1;
    const int l0 = lk(k0), l1 = lk(k1);
    float2 c0v = *reinterpret_cast<const float2*>(fp + 2 * p);
    float2 p2v = *reinterpret_cast<const float2*>(&Gf[r * 40 + k0]);
    float p10 = bf2f(CO[r * STRC + k0]);
    float p11 = bf2f(CO[r * STRC + k1]);
    float2 o;
    o.x = wn0[l0] * c0v.x + wn1[l0] * p10 + wn2[l0] * p2v.x;
    o.y = wn0[l1] * c0v.y + wn1[l1] * p11 + wn2[l1] * p2v.y;
    *reinterpret_cast<float2*>(op + 2 * p) = o;
  }
}

__global__ __launch_bounds__(256, 2)
void gaunt_mfma_kernel(const float* __restrict__ feat,
                       const float* __restrict__ atype,
                       const float* __restrict__ wts,
                       float* __restrict__ out) {
  __shared__ unsigned short CO[128 * STRC];  // 20480 B: c0, later prod1 (bf16)
  __shared__ unsigned short G[128 * STRG];   // 43008 B: grid g1/g2 (bf16), later prod2 (f32)
  float* Gf = reinterpret_cast<float*>(G);   // f32 view, row stride 40 floats (160 B)

  const int tid = threadIdx.x;
  const int atom = blockIdx.x;
  const int w = tid >> 6, lane = tid & 63, q = lane >> 4, l16 = lane & 15;
  const size_t fbase = (size_t)atom * 4608;

  // ---- stage c0 -> CO (bf16); zero K-pad cols 36..63 ----
#pragma unroll
  for (int it = 0; it < 18; ++it) {
    int i = tid + 256 * it;
    int row = i / 36, col = i - row * 36;
    CO[row * STRC + col] = bfr(feat[fbase + i]);
  }
#pragma unroll
  for (int it = 0; it < 14; ++it) {
    int j = tid + 256 * it;
    int row = j / 28, col = 36 + (j - row * 28);
    CO[row * STRC + col] = 0;
  }
  __syncthreads();

  // ---- GEMM1: f = c0 * Y'  (per wave: mtiles 2w,2w+1 x ntiles 0..9) ----
  f32x4 accA[2][10];
#pragma unroll
  for (int mi = 0; mi < 2; ++mi)
#pragma unroll
    for (int nt = 0; nt < 10; ++nt) accA[mi][nt] = f32x4{0.f, 0.f, 0.f, 0.f};

#pragma unroll
  for (int ks = 0; ks < 2; ++ks) {
    short8 af[2];
#pragma unroll
    for (int mi = 0; mi < 2; ++mi)
      af[mi] = *reinterpret_cast<const short8*>(&CO[((2 * w + mi) * 16 + l16) * STRC + ks * 32 + q * 8]);
#pragma unroll
    for (int nt = 0; nt < 10; ++nt) {
      short8 bf = *reinterpret_cast<const short8*>(&SYNB.v[((ks * 10 + nt) * 64 + lane) * 4]);
      accA[0][nt] = __builtin_amdgcn_mfma_f32_16x16x32_bf16(af[0], bf, accA[0][nt], 0, 0, 0);
      accA[1][nt] = __builtin_amdgcn_mfma_f32_16x16x32_bf16(af[1], bf, accA[1][nt], 0, 0, 0);
    }
  }

  // ---- pointwise: keep f (packed bf16) in regs; write g1 = f*f to G ----
  unsigned fpk[2][10][2];
#pragma unroll
  for (int mi = 0; mi < 2; ++mi)
#pragma unroll
    for (int nt = 0; nt < 10; ++nt) {
      f32x4 v = accA[mi][nt];
      const int r0 = (2 * w + mi) * 16 + q * 4;
      const int col = nt * 16 + l16;
      unsigned b0 = bfr(v.x), b1 = bfr(v.y), b2 = bfr(v.z), b3 = bfr(v.w);
      fpk[mi][nt][0] = b0 | (b1 << 16);
      fpk[mi][nt][1] = b2 | (b3 << 16);
      G[(r0 + 0) * STRG + col] = bfr(v.x * v.x);
      G[(r0 + 1) * STRG + col] = bfr(v.y * v.y);
      G[(r0 + 2) * STRG + col] = bfr(v.z * v.z);
      G[(r0 + 3) * STRG + col] = bfr(v.w * v.w);
    }
  __syncthreads();

  // ---- GEMM2: prod1 = g1 * Yw'  (mtiles 2w,2w+1 x ntiles 0..2, K=160) ----
  f32x4 acc2[2][3];
#pragma unroll
  for (int mi = 0; mi < 2; ++mi)
#pragma unroll
    for (int nt = 0; nt < 3; ++nt) acc2[mi][nt] = f32x4{0.f, 0.f, 0.f, 0.f};

#pragma unroll
  for (int ks = 0; ks < 5; ++ks) {
    short8 ga[2];
#pragma unroll
    for (int mi = 0; mi < 2; ++mi)
      ga[mi] = *reinterpret_cast<const short8*>(&G[((2 * w + mi) * 16 + l16) * STRG + ks * 32 + q * 8]);
#pragma unroll
    for (int nt = 0; nt < 3; ++nt) {
      short8 bf = *reinterpret_cast<const short8*>(&ANAB.v[((ks * 3 + nt) * 64 + lane) * 4]);
      acc2[0][nt] = __builtin_amdgcn_mfma_f32_16x16x32_bf16(ga[0], bf, acc2[0][nt], 0, 0, 0);
      acc2[1][nt] = __builtin_amdgcn_mfma_f32_16x16x32_bf16(ga[1], bf, acc2[1][nt], 0, 0, 0);
    }
  }

  // write prod1 (bf16) into CO cols 0..47 (36..47 are zeros; 48..63 stay zero)
#pragma unroll
  for (int mi = 0; mi < 2; ++mi)
#pragma unroll
    for (int nt = 0; nt < 3; ++nt) {
      f32x4 v = acc2[mi][nt];
      const int r0 = (2 * w + mi) * 16 + q * 4;
      const int col = nt * 16 + l16;
      CO[(r0 + 0) * STRC + col] = bfr(v.x);
      CO[(r0 + 1) * STRC + col] = bfr(v.y);
      CO[(r0 + 2) * STRC + col] = bfr(v.z);
      CO[(r0 + 3) * STRC + col] = bfr(v.w);
    }
  __syncthreads();

  // ---- GEMM3: f2 = prod1 * Y' ; g2 = f2 * f -> G ----
  f32x4 acc3[2][10];
#pragma unroll
  for (int mi = 0; mi < 2; ++mi)
#pragma unroll
    for (int nt = 0; nt < 10; ++nt) acc3[mi][nt] = f32x4{0.f, 0.f, 0.f, 0.f};

#pragma unroll
  for (int ks = 0; ks < 2; ++ks) {
    short8 af[2];
#pragma unroll
    for (int mi = 0; mi < 2; ++mi)
      af[mi] = *reinterpret_cast<const short8*>(&CO[((2 * w + mi) * 16 + l16) * STRC + ks * 32 + q * 8]);
#pragma unroll
    for (int nt = 0; nt < 10; ++nt) {
      short8 bf = *reinterpret_cast<const short8*>(&SYNB.v[((ks * 10 + nt) * 64 + lane) * 4]);
      acc3[0][nt] = __builtin_amdgcn_mfma_f32_16x16x32_bf16(af[0], bf, acc3[0][nt], 0, 0, 0);
      acc3[1][nt] = __builtin_amdgcn_mfma_f32_16x16x32_bf16(af[1], bf, acc3[1][nt], 0, 0, 0);
    }
  }

#pragma unroll
  for (int mi = 0; mi < 2; ++mi)
#pragma unroll
    for (int nt = 0; nt < 10; ++nt) {
      f32x4 v = acc3[mi][nt];
      const int r0 = (2 * w + mi) * 16 + q * 4;
      const int col = nt * 16 + l16;
      float f0 = __uint_as_float(fpk[mi][nt][0] << 16);
      float f1 = __uint_as_float(fpk[mi][nt][0] & 0xFFFF0000u);
      float f2_ = __uint_as_float(fpk[mi][nt][1] << 16);
      float f3 = __uint_as_float(fpk[mi][nt][1] & 0xFFFF0000u);
      G[(r0 + 0) * STRG + col] = bfr(v.x * f0);
      G[(r0 + 1) * STRG + col] = bfr(v.y * f1);
      G[(r0 + 2) * STRG + col] = bfr(v.z * f2_);
      G[(r0 + 3) * STRG + col] = bfr(v.w * f3);
    }
  __syncthreads();

  // ---- GEMM4: prod2 = g2 * Yw' ----
  f32x4 acc4[2][3];
#pragma unroll
  for (int mi = 0; mi < 2; ++mi)
#pragma unroll
    for (int nt = 0; nt < 3; ++nt) acc4[mi][nt] = f32x4{0.f, 0.f, 0.f, 0.f};

#pragma unroll
  for (int ks = 0; ks < 5; ++ks) {
    short8 ga[2];
#pragma unroll
    for (int mi = 0; mi < 2; ++mi)
      ga[mi] = *reinterpret_cast<const short8*>(&G[((2 * w + mi) * 16 + l16) * STRG + ks * 32 + q * 8]);
#pragma unroll
    for (int nt = 0; nt < 3; ++nt) {
      short8 bf = *reinterpret_cast<const short8*>(&ANAB.v[((ks * 3 + nt) * 64 + lane) * 4]);
      acc4[0][nt] = __builtin_amdgcn_mfma_f32_16x16x32_bf16(ga[0], bf, acc4[0][nt], 0, 0, 0);
      acc4[1][nt] = __builtin_amdgcn_mfma_f32_16x16x32_bf16(ga[1], bf, acc4[1][nt], 0, 0, 0);
    }
  }
  __syncthreads();  // all waves done reading G before overwriting with f32 prod2

#pragma unroll
  for (int mi = 0; mi < 2; ++mi)
#pragma unroll
    for (int nt = 0; nt < 3; ++nt) {
      const int col = nt * 16 + l16;
      if (col < 36) {
        f32x4 v = acc4[mi][nt];
        const int r0 = (2 * w + mi) * 16 + q * 4;
        Gf[(r0 + 0) * 40 + col] = v.x;
        Gf[(r0 + 1) * 40 + col] = v.y;
        Gf[(r0 + 2) * 40 + col] = v.z;
        Gf[(r0 + 3) * 40 + col] = v.w;
      }
    }
  __syncthreads();

  // ---- epilogue: out = wn0*c0 + wn1*prod1 + wn2*prod2 ----
  const int half = tid >> 7;
  const int r = tid & 127;

  float at[10];
#pragma unroll
  for (int e = 0; e < 10; ++e) at[e] = atype[atom * 10 + e];

  float wn0[6], wn1[6], wn2[6];
#pragma unroll
  for (int l = 0; l < 6; ++l) { wn0[l] = 0.f; wn1[l] = 0.f; wn2[l] = 0.f; }
#pragma unroll
  for (int e = 0; e < 10; ++e) {
    const float* w0p = wts + ((size_t)(0 * 10 + e) * 128 + r) * 6;
    const float* w1p = wts + ((size_t)(1 * 10 + e) * 128 + r) * 6;
    const float* w2p = wts + ((size_t)(2 * 10 + e) * 128 + r) * 6;
#pragma unroll
    for (int l = 0; l < 6; ++l) {
      wn0[l] += at[e] * w0p[l];
      wn1[l] += at[e] * w1p[l];
      wn2[l] += at[e] * w2p[l];
    }
  }

  const float* fp = feat + fbase + (size_t)r * 36 + half * 18;
  float* op = out + fbase + (size_t)r * 36 + half * 18;
  if (half == 0) epilogue_half<0>(r, fp, op, CO, Gf, wn0, wn1, wn2);
  else           epilogue_half<18>(r, fp, op, CO, Gf, wn0, wn1, wn2);
}

extern "C" void kernel_launch(void* const* d_in, const int* in_sizes, int n_in,
                              void* d_out, int out_size, void* d_ws, size_t ws_size,
                              hipStream_t stream) {
  const float* feat = (const float*)d_in[0];   // [4096,128,36] f32
  const float* atype = (const float*)d_in[1];  // [4096,10] f32
  const float* wts = (const float*)d_in[2];    // [3,10,128,6] f32
  float* out = (float*)d_out;                  // [4096,128,36] f32
  (void)in_sizes; (void)n_in; (void)out_size; (void)d_ws; (void)ws_size;

  gaunt_mfma_kernel<<<4096, 256, 0, stream>>>(feat, atype, wts, out);
}

// Round 3
// 227.019 us; speedup vs baseline: 1.2908x; 1.2908x over previous
//
#include <hip/hip_runtime.h>
#include <stdint.h>

// ---------------------------------------------------------------------------
// Compile-time tables + fragment-packed bf16 constant B matrices for
// MFMA 32x32x16 bf16.  B-frag layout: lane l holds B[k = ks*16 + (l>>5)*8 + j]
// [n = ntile*32 + (l&31)], j=0..7 packed as 4 dwords (lo16 = even j).
// SYN = Y'  [K=48 (36 real) x N=160 (144 real grid pts)]  (synthesis)
// ANA = Yw' [K=144 x N=64 (36 real coeffs)]               (analysis)
// ---------------------------------------------------------------------------
namespace ct {

constexpr double PI_ = 3.14159265358979323846;

constexpr double csqrt(double x) {
  double g = x > 1.0 ? x : 1.0;
  for (int i = 0; i < 40; ++i) g = 0.5 * (g + x / g);
  return g;
}
constexpr double ccos(double x) {  // |x| <= pi
  double x2 = x * x, t = 1.0, s = 1.0;
  for (int k = 1; k <= 16; ++k) { t *= -x2 / ((2.0 * k - 1.0) * (2.0 * k)); s += t; }
  return s;
}
constexpr double csin(double x) {  // |x| <= pi
  double x2 = x * x, t = x, s = x;
  for (int k = 1; k <= 16; ++k) { t *= -x2 / ((2.0 * k) * (2.0 * k + 1.0)); s += t; }
  return s;
}

struct GL { double x[12]; double w[12]; };

constexpr GL gl12() {
  GL g{};
  for (int i = 0; i < 12; ++i) {
    double x = ccos(PI_ * (i + 0.75) / 12.5);
    for (int it = 0; it < 50; ++it) {
      double p0 = 1.0, p1 = x;
      for (int k = 2; k <= 12; ++k) { double pk = ((2.0 * k - 1.0) * x * p1 - (k - 1.0) * p0) / k; p0 = p1; p1 = pk; }
      double dp = 12.0 * (x * p1 - p0) / (x * x - 1.0);
      x -= p1 / dp;
    }
    double p0 = 1.0, p1 = x;
    for (int k = 2; k <= 12; ++k) { double pk = ((2.0 * k - 1.0) * x * p1 - (k - 1.0) * p0) / k; p0 = p1; p1 = pk; }
    double dp = 12.0 * (x * p1 - p0) / (x * x - 1.0);
    g.x[i] = x;
    g.w[i] = 2.0 / ((1.0 - x * x) * dp * dp);
  }
  return g;
}

struct Tab {
  double PA[12][36];   // Pbar_l^{|m|}(x_b) by SH index k
  double PB[12][36];   // PA * wq[b] * (2*pi/12)
  double ANG[12][36];  // angular factor at alpha_a for SH index k
};

constexpr Tab make_tab() {
  Tab t{};
  GL g = gl12();
  for (int b = 0; b < 12; ++b) {
    double x = g.x[b];
    double s = csqrt(1.0 - x * x);
    double P[6][6] = {};
    P[0][0] = csqrt(1.0 / (4.0 * PI_));
    for (int m = 1; m <= 5; ++m) P[m][m] = csqrt((2.0 * m + 1.0) / (2.0 * m)) * s * P[m - 1][m - 1];
    for (int m = 0; m < 5; ++m)  P[m + 1][m] = csqrt(2.0 * m + 3.0) * x * P[m][m];
    for (int m = 0; m <= 5; ++m)
      for (int l = m + 2; l <= 5; ++l) {
        double aa = csqrt((4.0 * l * l - 1.0) / (double)(l * l - m * m));
        double bb = csqrt(((l - 1.0) * (l - 1.0) - (double)(m * m)) / (4.0 * (l - 1.0) * (l - 1.0) - 1.0));
        P[l][m] = aa * (x * P[l - 1][m] - bb * P[l - 2][m]);
      }
    for (int l = 0; l <= 5; ++l)
      for (int m = -l; m <= l; ++m) {
        int k = l * l + l + m, am = m < 0 ? -m : m;
        t.PA[b][k] = P[l][am];
        t.PB[b][k] = P[l][am] * g.w[b] * (2.0 * PI_ / 12.0);
      }
  }
  double r2 = csqrt(2.0);
  for (int a = 0; a < 12; ++a)
    for (int l = 0; l <= 5; ++l)
      for (int m = -l; m <= l; ++m) {
        int k = l * l + l + m, am = m < 0 ? -m : m;
        double v = 1.0;
        if (m != 0) {
          int qq = (am * a) % 12;  // exact angle reduction: angle = 2*pi*qq/12
          double ang = 2.0 * PI_ * qq / 12.0;
          if (ang > PI_) ang -= 2.0 * PI_;
          v = (m > 0) ? r2 * ccos(ang) : r2 * csin(ang);
        }
        t.ANG[a][k] = v;
      }
  return t;
}

constexpr Tab TD = make_tab();

// float -> bf16 bits (round-to-nearest-even), pure-arithmetic constexpr.
constexpr unsigned f2bf(double x) {
  if (x == 0.0) return 0u;
  unsigned s = 0u; double a = x;
  if (a < 0.0) { s = 0x8000u; a = -a; }
  int e = 127;
  while (a >= 2.0) { a *= 0.5; ++e; }
  while (a < 1.0)  { a *= 2.0; --e; }
  double md = (a - 1.0) * 128.0;
  int mi = (int)md;
  double fr = md - mi;
  if (fr > 0.5 || (fr == 0.5 && (mi & 1))) ++mi;
  if (mi == 128) { mi = 0; ++e; }
  return s | ((unsigned)e << 7) | (unsigned)mi;
}

constexpr double syn_val(int k, int n) {  // Y'[k][n], n = b*12 + a
  if (k >= 36 || n >= 144) return 0.0;
  int b = n / 12, a = n % 12;
  return TD.PA[b][k] * TD.ANG[a][k];
}
constexpr double ana_val(int kp, int np) {  // Yw'[kp][np], kp = b*12 + a
  if (kp >= 144 || np >= 36) return 0.0;
  int b = kp / 12, a = kp % 12;
  return TD.PB[b][np] * TD.ANG[a][np];
}

struct alignas(16) Syn32 { unsigned v[3 * 5 * 64 * 4]; };  // 15360 B
struct alignas(16) Ana32 { unsigned v[9 * 2 * 64 * 4]; };  // 18432 B

constexpr Syn32 make_syn32() {
  Syn32 F{};
  for (int ks = 0; ks < 3; ++ks)
    for (int nt = 0; nt < 5; ++nt)
      for (int lane = 0; lane < 64; ++lane)
        for (int jp = 0; jp < 4; ++jp) {
          int h = lane >> 5, n = nt * 32 + (lane & 31);
          int k0 = ks * 16 + h * 8 + jp * 2;
          F.v[((ks * 5 + nt) * 64 + lane) * 4 + jp] =
              f2bf(syn_val(k0, n)) | (f2bf(syn_val(k0 + 1, n)) << 16);
        }
  return F;
}
constexpr Ana32 make_ana32() {
  Ana32 F{};
  for (int ks = 0; ks < 9; ++ks)
    for (int nt = 0; nt < 2; ++nt)
      for (int lane = 0; lane < 64; ++lane)
        for (int jp = 0; jp < 4; ++jp) {
          int h = lane >> 5, n = nt * 32 + (lane & 31);
          int k0 = ks * 16 + h * 8 + jp * 2;
          F.v[((ks * 2 + nt) * 64 + lane) * 4 + jp] =
              f2bf(ana_val(k0, n)) | (f2bf(ana_val(k0 + 1, n)) << 16);
        }
  return F;
}

}  // namespace ct

__device__ constexpr ct::Syn32 SYNB = ct::make_syn32();
__device__ constexpr ct::Ana32 ANAB = ct::make_ana32();

typedef __attribute__((ext_vector_type(8))) short short8;
typedef __attribute__((ext_vector_type(16))) float f32x16;

union S8 { short8 s; unsigned u[4]; uint2 u2[2]; };

__device__ __forceinline__ unsigned short bfr(float x) {
  return (unsigned short)((__float_as_uint(x) + 0x8000u) >> 16);
}
__device__ __forceinline__ unsigned pk2(float x, float y) {
  return (unsigned)bfr(x) | ((unsigned)bfr(y) << 16);
}
__device__ __forceinline__ float lo16(unsigned u) { return __uint_as_float(u << 16); }
__device__ __forceinline__ float hi16(unsigned u) { return __uint_as_float(u & 0xFFFF0000u); }

__device__ __forceinline__ short8 synf(int ks, int nt, int lane) {
  const uint4* p = reinterpret_cast<const uint4*>(SYNB.v) + (ks * 5 + nt) * 64 + lane;
  uint4 t = *p; S8 r; r.u[0] = t.x; r.u[1] = t.y; r.u[2] = t.z; r.u[3] = t.w; return r.s;
}
__device__ __forceinline__ short8 anaf(int ks, int nt, int lane) {
  const uint4* p = reinterpret_cast<const uint4*>(ANAB.v) + (ks * 2 + nt) * 64 + lane;
  uint4 t = *p; S8 r; r.u[0] = t.x; r.u[1] = t.y; r.u[2] = t.z; r.u[3] = t.w; return r.s;
}

#define FWS 148  // FW row stride (ushorts): 296 B (8B-aligned; 74 dw % 32 = 10 -> 2-way reads)
#define COS 52   // CO row stride (ushorts): 104 B (26 dw % 32 = 26 -> 2-way reads)

// One wave = one 32-row tile (rows = atom*128 + ch). Block = 2 independent
// waves; NO __syncthreads anywhere (all LDS sharing is intra-wave).
__global__ __launch_bounds__(128, 2)
void gaunt32_kernel(const float* __restrict__ feat,
                    const float* __restrict__ atype,
                    const float* __restrict__ wts,
                    float* __restrict__ out) {
  __shared__ unsigned short FW[2][32 * FWS];  // 18944 B: grid g1 / g2 (bf16)
  __shared__ unsigned short CO[2][32 * COS];  // 6656 B: prod1 (bf16), K-padded to 48
  __shared__ float WN[2][18 * 32];            // 4608 B: wn[nu*6+l][ch]

  const int tid = threadIdx.x;
  const int ws = __builtin_amdgcn_readfirstlane(tid >> 6);  // wave id (SGPR)
  const int lane = tid & 63;
  const int m = lane & 31, h = lane >> 5;
  const int mtile = blockIdx.x * 2 + ws;
  const int rowbase = mtile * 32;
  const int atom = mtile >> 2;         // 4 tiles per atom
  const int chb = (mtile & 3) * 32;    // channel base within atom

  unsigned short* fw = FW[ws];
  unsigned short* co = CO[ws];
  float* wn = WN[ws];

  // ---- A-frags for GEMM1 straight from global (row m, k = ks*16 + h*8 + j) ----
  const float* fr = feat + (rowbase + m) * 36;
  S8 af[3];
  {
    float4 a = *reinterpret_cast<const float4*>(fr + h * 8);
    float4 b = *reinterpret_cast<const float4*>(fr + h * 8 + 4);
    af[0].u[0] = pk2(a.x, a.y); af[0].u[1] = pk2(a.z, a.w);
    af[0].u[2] = pk2(b.x, b.y); af[0].u[3] = pk2(b.z, b.w);
    a = *reinterpret_cast<const float4*>(fr + 16 + h * 8);
    b = *reinterpret_cast<const float4*>(fr + 20 + h * 8);
    af[1].u[0] = pk2(a.x, a.y); af[1].u[1] = pk2(a.z, a.w);
    af[1].u[2] = pk2(b.x, b.y); af[1].u[3] = pk2(b.z, b.w);
    af[2].u[0] = 0; af[2].u[1] = 0; af[2].u[2] = 0; af[2].u[3] = 0;
    if (h == 0) {  // k = 32..35 real, 36..39 zero (B rows >=36 are zero anyway)
      a = *reinterpret_cast<const float4*>(fr + 32);
      af[2].u[0] = pk2(a.x, a.y); af[2].u[1] = pk2(a.z, a.w);
    }
  }

  // ---- GEMM1: f = c0 * Y'  (M=32, K=48, N=160); g1 = f*f -> FW; keep f bf16 in fpk ----
  unsigned fpk[5][8];
#pragma unroll
  for (int nt = 0; nt < 5; ++nt) {
    f32x16 acc = {0.f, 0.f, 0.f, 0.f, 0.f, 0.f, 0.f, 0.f,
                  0.f, 0.f, 0.f, 0.f, 0.f, 0.f, 0.f, 0.f};
#pragma unroll
    for (int ks = 0; ks < 3; ++ks)
      acc = __builtin_amdgcn_mfma_f32_32x32x16_bf16(af[ks].s, synf(ks, nt, lane), acc, 0, 0, 0);
    const int col = nt * 32 + m;
#pragma unroll
    for (int g = 0; g < 4; ++g) {
      fpk[nt][2 * g + 0] = pk2(acc[4 * g + 0], acc[4 * g + 1]);
      fpk[nt][2 * g + 1] = pk2(acc[4 * g + 2], acc[4 * g + 3]);
    }
    if (col < 144) {
#pragma unroll
      for (int g = 0; g < 4; ++g)
#pragma unroll
        for (int i = 0; i < 4; ++i) {
          float v = acc[4 * g + i];
          fw[(i + 8 * g + 4 * h) * FWS + col] = bfr(v * v);
        }
    }
  }

  // ---- GEMM2: prod1 = g1 * Yw'  (M=32, K=144, N=64) ----
  S8 ga[9];
  {
    const unsigned short* fr2 = &fw[m * FWS + h * 8];
#pragma unroll
    for (int ks = 0; ks < 9; ++ks) {
      ga[ks].u2[0] = *reinterpret_cast<const uint2*>(fr2 + ks * 16);
      ga[ks].u2[1] = *reinterpret_cast<const uint2*>(fr2 + ks * 16 + 4);
    }
  }
  f32x16 p1[2];
#pragma unroll
  for (int nt = 0; nt < 2; ++nt) {
    f32x16 acc = {0.f, 0.f, 0.f, 0.f, 0.f, 0.f, 0.f, 0.f,
                  0.f, 0.f, 0.f, 0.f, 0.f, 0.f, 0.f, 0.f};
#pragma unroll
    for (int ks = 0; ks < 9; ++ks)
      acc = __builtin_amdgcn_mfma_f32_32x32x16_bf16(ga[ks].s, anaf(ks, nt, lane), acc, 0, 0, 0);
    p1[nt] = acc;
  }

  // ---- prod1 (bf16) -> CO, cols 0..47 (36..47 are exact zeros from N-pad) ----
#pragma unroll
  for (int nt = 0; nt < 2; ++nt) {
    const int col = nt * 32 + m;
    if (col < 48) {
#pragma unroll
      for (int g = 0; g < 4; ++g)
#pragma unroll
        for (int i = 0; i < 4; ++i)
          co[(i + 8 * g + 4 * h) * COS + col] = bfr(p1[nt][4 * g + i]);
    }
  }

  // ---- GEMM3: f2 = prod1 * Y' ; g2 = f2 * f -> FW ----
  S8 ca[3];
  {
    const unsigned short* cr = &co[m * COS + h * 8];
#pragma unroll
    for (int ks = 0; ks < 3; ++ks) {
      ca[ks].u2[0] = *reinterpret_cast<const uint2*>(cr + ks * 16);
      ca[ks].u2[1] = *reinterpret_cast<const uint2*>(cr + ks * 16 + 4);
    }
  }
#pragma unroll
  for (int nt = 0; nt < 5; ++nt) {
    f32x16 acc = {0.f, 0.f, 0.f, 0.f, 0.f, 0.f, 0.f, 0.f,
                  0.f, 0.f, 0.f, 0.f, 0.f, 0.f, 0.f, 0.f};
#pragma unroll
    for (int ks = 0; ks < 3; ++ks)
      acc = __builtin_amdgcn_mfma_f32_32x32x16_bf16(ca[ks].s, synf(ks, nt, lane), acc, 0, 0, 0);
    const int col = nt * 32 + m;
    if (col < 144) {
#pragma unroll
      for (int g = 0; g < 4; ++g)
#pragma unroll
        for (int i = 0; i < 4; ++i) {
          unsigned pk = fpk[nt][2 * g + (i >> 1)];
          float f = (i & 1) ? hi16(pk) : lo16(pk);
          fw[(i + 8 * g + 4 * h) * FWS + col] = bfr(acc[4 * g + i] * f);
        }
    }
  }

  // ---- GEMM4: prod2 = g2 * Yw' ----
  {
    const unsigned short* fr2 = &fw[m * FWS + h * 8];
#pragma unroll
    for (int ks = 0; ks < 9; ++ks) {
      ga[ks].u2[0] = *reinterpret_cast<const uint2*>(fr2 + ks * 16);
      ga[ks].u2[1] = *reinterpret_cast<const uint2*>(fr2 + ks * 16 + 4);
    }
  }
  f32x16 p2[2];
#pragma unroll
  for (int nt = 0; nt < 2; ++nt) {
    f32x16 acc = {0.f, 0.f, 0.f, 0.f, 0.f, 0.f, 0.f, 0.f,
                  0.f, 0.f, 0.f, 0.f, 0.f, 0.f, 0.f, 0.f};
#pragma unroll
    for (int ks = 0; ks < 9; ++ks)
      acc = __builtin_amdgcn_mfma_f32_32x32x16_bf16(ga[ks].s, anaf(ks, nt, lane), acc, 0, 0, 0);
    p2[nt] = acc;
  }

  // ---- wn[nu*6+l][ch] = sum_e atype[atom][e] * wts[nu][e][chb+ch][l] ----
  {
    float at[10];
#pragma unroll
    for (int e = 0; e < 10; ++e) at[e] = atype[atom * 10 + e];
#pragma unroll
    for (int t = 0; t < 9; ++t) {
      const int p = h + 2 * t;  // 0..17, each exactly once per half-wave
      const int nu = p >= 12 ? 2 : (p >= 6 ? 1 : 0);
      const int l = p - nu * 6;
      const float* wb = wts + ((nu * 10) * 128 + chb + m) * 6 + l;
      float s = 0.f;
#pragma unroll
      for (int e = 0; e < 10; ++e) s += at[e] * wb[e * 768];
      wn[p * 32 + m] = s;
    }
  }

  // ---- epilogue: out = wn0*c0 + wn1*prod1 + wn2*prod2 (all in C-layout) ----
#pragma unroll
  for (int nt = 0; nt < 2; ++nt) {
    const int col = nt * 32 + m;
    if (col < 36) {
      const int lc = col >= 25 ? 5 : col >= 16 ? 4 : col >= 9 ? 3 : col >= 4 ? 2 : col >= 1 ? 1 : 0;
#pragma unroll
      for (int g = 0; g < 4; ++g)
#pragma unroll
        for (int i = 0; i < 4; ++i) {
          const int row = i + 8 * g + 4 * h;
          const float c0 = feat[(rowbase + row) * 36 + col];
          const float w0 = wn[(lc + 0) * 32 + row];
          const float w1 = wn[(lc + 6) * 32 + row];
          const float w2 = wn[(lc + 12) * 32 + row];
          out[(size_t)(rowbase + row) * 36 + col] =
              w0 * c0 + w1 * p1[nt][4 * g + i] + w2 * p2[nt][4 * g + i];
        }
    }
  }
}

extern "C" void kernel_launch(void* const* d_in, const int* in_sizes, int n_in,
                              void* d_out, int out_size, void* d_ws, size_t ws_size,
                              hipStream_t stream) {
  const float* feat = (const float*)d_in[0];   // [4096,128,36] f32
  const float* atype = (const float*)d_in[1];  // [4096,10] f32
  const float* wts = (const float*)d_in[2];    // [3,10,128,6] f32
  float* out = (float*)d_out;                  // [4096,128,36] f32
  (void)in_sizes; (void)n_in; (void)out_size; (void)d_ws; (void)ws_size;

  // 524288 rows / 32 per wave = 16384 tiles; 2 waves per block -> 8192 blocks.
  gaunt32_kernel<<<8192, 128, 0, stream>>>(feat, atype, wts, out);
}